// Round 1
// baseline (505.897 us; speedup 1.0000x reference)
//
#include <hip/hip_runtime.h>
#include <hip/hip_bf16.h>
#include <stdint.h>

#define S_LEN 2048
#define NB 2
#define NH 16
#define DM 1024
#define KDIM 64
#define MTOK (NB*S_LEN)   // 4096 tokens

typedef __attribute__((ext_vector_type(8))) short bf16x8;
typedef __attribute__((ext_vector_type(4))) float f32x4;
typedef __attribute__((ext_vector_type(4))) unsigned short u16x4;

#define AS1 __attribute__((address_space(1)))
#define AS3 __attribute__((address_space(3)))

__device__ __forceinline__ unsigned short f2bf(float f) {
  unsigned int u = __builtin_bit_cast(unsigned int, f);
  return (unsigned short)((u + 0x7fffu + ((u >> 16) & 1u)) >> 16);   // RNE
}

__device__ __forceinline__ f32x4 mfma16(bf16x8 a, bf16x8 b, f32x4 c) {
  return __builtin_amdgcn_mfma_f32_16x16x32_bf16(a, b, c, 0, 0, 0);
}

// ---------------------------------------------------------------------------
// fp32 -> bf16 convert, 7 segments (q,k,v inputs + Wq,Wk,Wv,Wo)
// ---------------------------------------------------------------------------
struct CvtArgs {
  const float* src[7];
  unsigned short* dst[7];
  int n[7];
};

__global__ __launch_bounds__(256) void cvt_f32_bf16(CvtArgs a) {
  const int seg = blockIdx.y;
  const float* __restrict__ s = a.src[seg];
  unsigned short* __restrict__ d = a.dst[seg];
  const int n4 = a.n[seg] >> 2;
  const int stride = gridDim.x * blockDim.x;
  for (int i = blockIdx.x * blockDim.x + threadIdx.x; i < n4; i += stride) {
    const float4 v = reinterpret_cast<const float4*>(s)[i];
    u16x4 o;
    o[0] = f2bf(v.x); o[1] = f2bf(v.y); o[2] = f2bf(v.z); o[3] = f2bf(v.w);
    reinterpret_cast<u16x4*>(d)[i] = o;
  }
}

// ---------------------------------------------------------------------------
// GEMM: C[m,n] = sum_k A[m,k]*Bw[n,k] + bias[n]   (A,Bw bf16 row-major, K-contig)
// 128x128 tile, BK=32, 4 waves (2x2), global_load_lds width-16 staging.
// MODE 0: bf16 out scattered to [b,h,s,d]   (Q, K)
// MODE 1: bf16 out scattered to [b,h,d,s]   (V transposed)
// MODE 2: fp32 out row-major [M,N]          (final projection)
// ---------------------------------------------------------------------------
template<int MODE>
__global__ __launch_bounds__(256, 2)
void gemm_bt(const unsigned short* __restrict__ A,
             const unsigned short* __restrict__ Bw,
             const float* __restrict__ bias,
             void* __restrict__ dst,
             const int M, const int N, const int K)
{
  __shared__ __align__(16) unsigned short As[128*32];
  __shared__ __align__(16) unsigned short Bs[128*32];
  const int t = threadIdx.x;
  const int w = t >> 6, l = t & 63;
  const int g = l >> 4, cl = l & 15;
  const int m0 = blockIdx.y * 128;
  const int n0 = blockIdx.x * 128;

  // staging: thread t loads 16B; LDS is linear [row][32] bf16 (64B rows)
  const unsigned short* Ag = A + (size_t)(m0 + (t >> 2)) * K + (t & 3) * 8;
  const unsigned short* Bg = Bw + (size_t)(n0 + (t >> 2)) * K + (t & 3) * 8;
  AS3 unsigned short* lA = (AS3 unsigned short*)As + w * 512;   // wave-uniform base
  AS3 unsigned short* lB = (AS3 unsigned short*)Bs + w * 512;

  const int wm = (w >> 1) * 64, wn = (w & 1) * 64;

  f32x4 acc[4][4];
  for (int i = 0; i < 4; ++i) for (int j = 0; j < 4; ++j) acc[i][j] = 0.f;

  for (int kt = 0; kt < K; kt += 32) {
    __builtin_amdgcn_global_load_lds((const AS1 void*)(Ag + kt),                   (AS3 void*)lA,          16, 0, 0);
    __builtin_amdgcn_global_load_lds((const AS1 void*)(Ag + kt + (size_t)64 * K),  (AS3 void*)(lA + 2048), 16, 0, 0);
    __builtin_amdgcn_global_load_lds((const AS1 void*)(Bg + kt),                   (AS3 void*)lB,          16, 0, 0);
    __builtin_amdgcn_global_load_lds((const AS1 void*)(Bg + kt + (size_t)64 * K),  (AS3 void*)(lB + 2048), 16, 0, 0);
    __syncthreads();
    bf16x8 af[4], bfv[4];
    for (int i = 0; i < 4; ++i)
      af[i] = *reinterpret_cast<const bf16x8*>(&As[(wm + 16*i + cl) * 32 + g*8]);
    for (int j = 0; j < 4; ++j)
      bfv[j] = *reinterpret_cast<const bf16x8*>(&Bs[(wn + 16*j + cl) * 32 + g*8]);
    for (int i = 0; i < 4; ++i)
      for (int j = 0; j < 4; ++j)
        acc[i][j] = mfma16(af[i], bfv[j], acc[i][j]);
    __syncthreads();
  }

  // epilogue: D col = n (lane&15), row = m ((lane>>4)*4 + reg)  [m89-verified]
  for (int i = 0; i < 4; ++i) for (int j = 0; j < 4; ++j) {
    const int ncol = n0 + wn + 16*j + cl;
    const float bn = bias[ncol];
    for (int r = 0; r < 4; ++r) {
      const int m = m0 + wm + 16*i + g*4 + r;
      const float v = acc[i][j][r] + bn;
      if (MODE == 0) {
        const int b = m >> 11, s = m & (S_LEN-1);
        const int h = ncol >> 6, d = ncol & (KDIM-1);
        ((unsigned short*)dst)[((size_t)(b*NH + h)*S_LEN + s)*KDIM + d] = f2bf(v);
      } else if (MODE == 1) {
        const int b = m >> 11, s = m & (S_LEN-1);
        const int h = ncol >> 6, d = ncol & (KDIM-1);
        ((unsigned short*)dst)[((size_t)(b*NH + h)*KDIM + d)*S_LEN + s] = f2bf(v);
      } else {
        ((float*)dst)[(size_t)m * N + ncol] = v;
      }
    }
  }
}

// ---------------------------------------------------------------------------
// Fused attention: per (b,h) x 16-row Q tile.
// Pass A: QK^T tiles -> online (max, sumexp) per row (no score storage).
// Pass B: recompute tiles, p = exp(s-m)/l, write fp32 attn, PV via LDS bounce.
// ---------------------------------------------------------------------------
__global__ __launch_bounds__(256, 2)
void attn_fused(const unsigned short* __restrict__ Qh,
                const unsigned short* __restrict__ Kh,
                const unsigned short* __restrict__ Vt,
                float* __restrict__ attn,
                unsigned short* __restrict__ ctx)
{
  __shared__ float statM[4][16];
  __shared__ float statL[4][16];
  __shared__ float rowM[16], rowI[16];
  __shared__ __align__(16) unsigned short Pbuf[4][16][32];
  __shared__ __align__(16) float Obuf[4][16][64];

  const int bh = blockIdx.y;
  const int q0 = blockIdx.x * 16;
  const int t = threadIdx.x, w = t >> 6, l = t & 63;
  const int g = l >> 4, cl = l & 15;

  const unsigned short* Qb = Qh + ((size_t)bh * S_LEN + q0) * KDIM;
  const bf16x8 aq0 = *reinterpret_cast<const bf16x8*>(Qb + cl * KDIM + g * 8);
  const bf16x8 aq1 = *reinterpret_cast<const bf16x8*>(Qb + cl * KDIM + 32 + g * 8);

  const unsigned short* Kb = Kh + (size_t)bh * S_LEN * KDIM;
  const unsigned short* Vb = Vt + (size_t)bh * KDIM * S_LEN;

  // ---- pass A: stats over this wave's 512-col strip ----
  float m_r[4], l_r[4];
  for (int r = 0; r < 4; ++r) { m_r[r] = -1e30f; l_r[r] = 0.f; }

  for (int c = 0; c < 32; ++c) {
    const int scol = w * 512 + c * 16;
    const unsigned short* Kp = Kb + (size_t)(scol + cl) * KDIM + g * 8;
    const bf16x8 b0 = *reinterpret_cast<const bf16x8*>(Kp);
    const bf16x8 b1 = *reinterpret_cast<const bf16x8*>(Kp + 32);
    f32x4 acc = 0.f;
    acc = mfma16(aq0, b0, acc);
    acc = mfma16(aq1, b1, acc);
    for (int r = 0; r < 4; ++r) {
      const float v = acc[r] * 0.125f;           // /sqrt(64)
      const float nm = fmaxf(m_r[r], v);
      l_r[r] = l_r[r] * __expf(m_r[r] - nm) + __expf(v - nm);
      m_r[r] = nm;
    }
  }
  // combine across the 16 column-lanes (same row lives in lanes sharing l>>4)
  for (int mask = 1; mask <= 8; mask <<= 1) {
    for (int r = 0; r < 4; ++r) {
      const float om = __shfl_xor(m_r[r], mask, 64);
      const float ol = __shfl_xor(l_r[r], mask, 64);
      const float nm = fmaxf(m_r[r], om);
      l_r[r] = l_r[r] * __expf(m_r[r] - nm) + ol * __expf(om - nm);
      m_r[r] = nm;
    }
  }
  if (cl == 0)
    for (int r = 0; r < 4; ++r) { statM[w][g*4+r] = m_r[r]; statL[w][g*4+r] = l_r[r]; }
  __syncthreads();
  if (t < 16) {
    float m = statM[0][t], lsum = statL[0][t];
    for (int wv = 1; wv < 4; ++wv) {
      const float m2 = statM[wv][t], l2 = statL[wv][t];
      const float nm = fmaxf(m, m2);
      lsum = lsum * __expf(m - nm) + l2 * __expf(m2 - nm);
      m = nm;
    }
    rowM[t] = m;
    rowI[t] = 1.0f / lsum;
  }
  __syncthreads();

  float rm[4], ri[4];
  for (int r = 0; r < 4; ++r) { rm[r] = rowM[g*4+r]; ri[r] = rowI[g*4+r]; }

  // ---- pass B: recompute, normalize, write attn, PV ----
  f32x4 accP[4];
  for (int nt = 0; nt < 4; ++nt) accP[nt] = 0.f;
  float* adst = attn + ((size_t)bh * S_LEN + q0) * S_LEN;

  for (int c = 0; c < 16; ++c) {
    for (int sub = 0; sub < 2; ++sub) {
      const int scol = w * 512 + (c*2 + sub) * 16;
      const unsigned short* Kp = Kb + (size_t)(scol + cl) * KDIM + g * 8;
      const bf16x8 b0 = *reinterpret_cast<const bf16x8*>(Kp);
      const bf16x8 b1 = *reinterpret_cast<const bf16x8*>(Kp + 32);
      f32x4 acc = 0.f;
      acc = mfma16(aq0, b0, acc);
      acc = mfma16(aq1, b1, acc);
      for (int r = 0; r < 4; ++r) {
        const int row = g*4 + r;
        const float p = __expf(acc[r] * 0.125f - rm[r]) * ri[r];
        adst[(size_t)row * S_LEN + scol + cl] = p;       // fp32 attn out
        Pbuf[w][row][sub*16 + cl] = f2bf(p);             // LDS transpose bounce
      }
    }
    // PV over this 32-wide kv chunk (wave-private, wave-synchronous)
    const int kv0 = w * 512 + c * 32;
    const bf16x8 ap = *reinterpret_cast<const bf16x8*>(&Pbuf[w][cl][g*8]);
    for (int nt = 0; nt < 4; ++nt) {
      const unsigned short* Vp = Vb + (size_t)(nt*16 + cl) * S_LEN + kv0 + g*8;
      const bf16x8 bv = *reinterpret_cast<const bf16x8*>(Vp);
      accP[nt] = mfma16(ap, bv, accP[nt]);
    }
  }

  // cross-wave reduce of partial PV (each wave covered 512 of 2048 kv)
  for (int nt = 0; nt < 4; ++nt)
    for (int r = 0; r < 4; ++r)
      Obuf[w][g*4+r][nt*16+cl] = accP[nt][r];
  __syncthreads();
  {
    const int q = t >> 4, d0 = (t & 15) * 4;
    float s0 = 0.f, s1 = 0.f, s2 = 0.f, s3 = 0.f;
    for (int wv = 0; wv < 4; ++wv) {
      const float4 ob = *reinterpret_cast<const float4*>(&Obuf[wv][q][d0]);
      s0 += ob.x; s1 += ob.y; s2 += ob.z; s3 += ob.w;
    }
    u16x4 o;
    o[0] = f2bf(s0); o[1] = f2bf(s1); o[2] = f2bf(s2); o[3] = f2bf(s3);
    const int b = bh >> 4, h = bh & 15;
    *reinterpret_cast<u16x4*>(ctx + ((size_t)(b*S_LEN + q0 + q))*DM + h*KDIM + d0) = o;
  }
}

// ---------------------------------------------------------------------------
extern "C" void kernel_launch(void* const* d_in, const int* in_sizes, int n_in,
                              void* d_out, int out_size, void* d_ws, size_t ws_size,
                              hipStream_t stream)
{
  const float* q_in = (const float*)d_in[0];
  const float* k_in = (const float*)d_in[1];
  const float* v_in = (const float*)d_in[2];
  const float* Wq   = (const float*)d_in[3];
  const float* bq   = (const float*)d_in[4];
  const float* Wk   = (const float*)d_in[5];
  const float* bk   = (const float*)d_in[6];
  const float* Wv   = (const float*)d_in[7];
  const float* bv   = (const float*)d_in[8];
  const float* Wo   = (const float*)d_in[9];
  const float* bo   = (const float*)d_in[10];

  // workspace layout (all bf16 bit arrays), total ~67 MB
  unsigned short* qbf  = (unsigned short*)d_ws;
  unsigned short* kbf  = qbf  + (size_t)MTOK*DM;
  unsigned short* vbf  = kbf  + (size_t)MTOK*DM;
  unsigned short* wqbf = vbf  + (size_t)MTOK*DM;
  unsigned short* wkbf = wqbf + (size_t)DM*DM;
  unsigned short* wvbf = wkbf + (size_t)DM*DM;
  unsigned short* wobf = wvbf + (size_t)DM*DM;
  unsigned short* Qhp  = wobf + (size_t)DM*DM;    // [b,h,s,d]
  unsigned short* Khp  = Qhp  + (size_t)MTOK*DM;  // [b,h,s,d]
  unsigned short* Vtp  = Khp  + (size_t)MTOK*DM;  // [b,h,d,s]
  unsigned short* ctx  = Vtp  + (size_t)MTOK*DM;  // [b*s, h*d]

  float* out0 = (float*)d_out;
  float* attn = out0 + (size_t)MTOK*DM;

  CvtArgs ca;
  ca.src[0] = q_in; ca.dst[0] = qbf;  ca.n[0] = MTOK*DM;
  ca.src[1] = k_in; ca.dst[1] = kbf;  ca.n[1] = MTOK*DM;
  ca.src[2] = v_in; ca.dst[2] = vbf;  ca.n[2] = MTOK*DM;
  ca.src[3] = Wq;   ca.dst[3] = wqbf; ca.n[3] = DM*DM;
  ca.src[4] = Wk;   ca.dst[4] = wkbf; ca.n[4] = DM*DM;
  ca.src[5] = Wv;   ca.dst[5] = wvbf; ca.n[5] = DM*DM;
  ca.src[6] = Wo;   ca.dst[6] = wobf; ca.n[6] = DM*DM;
  cvt_f32_bf16<<<dim3(512, 7), 256, 0, stream>>>(ca);

  gemm_bt<0><<<dim3(8, 32), 256, 0, stream>>>(qbf, wqbf, bq, Qhp, MTOK, DM, DM);
  gemm_bt<0><<<dim3(8, 32), 256, 0, stream>>>(kbf, wkbf, bk, Khp, MTOK, DM, DM);
  gemm_bt<1><<<dim3(8, 32), 256, 0, stream>>>(vbf, wvbf, bv, Vtp, MTOK, DM, DM);

  attn_fused<<<dim3(S_LEN/16, NB*NH), 256, 0, stream>>>(Qhp, Khp, Vtp, attn, ctx);

  gemm_bt<2><<<dim3(8, 32), 256, 0, stream>>>(ctx, wobf, bo, (void*)out0, MTOK, DM, DM);
}